// Round 5
// baseline (1501.716 us; speedup 1.0000x reference)
//
#include <hip/hip_runtime.h>
#include <hip/hip_bf16.h>

#define D 64
#define THREADS 256
#define GTHREADS 512               // gather/deg blocks: 8 waves
#define BKT_BITS 9                 // 512 nodes per bucket
#define BKT_NODES (1 << BKT_BITS)
#define ASTRIDE 65                 // acc node stride (floats): 64+1 breaks bank alias
#define CHUNK 4096                 // edges per pass-1 block (391 blocks)

// ---- bf16 helpers (bit tricks, RNE) ----
__device__ __forceinline__ unsigned f2bf(float f) {
    unsigned u = __float_as_uint(f);
    return (u + 0x7fffu + ((u >> 16) & 1u)) >> 16;
}
__device__ __forceinline__ float2 bfpair(unsigned v) {
    return make_float2(__uint_as_float(v << 16), __uint_as_float(v & 0xffff0000u));
}

// ---- non-temporal store wrappers ----
typedef float f32x4 __attribute__((ext_vector_type(4)));
typedef unsigned u32x4 __attribute__((ext_vector_type(4)));
__device__ __forceinline__ void stnt_f4(float4 v, float4* p) {
    f32x4 t = {v.x, v.y, v.z, v.w};
    __builtin_nontemporal_store(t, (f32x4*)p);
}
__device__ __forceinline__ void stnt_u4(uint4 v, uint4* p) {
    u32x4 t = {v.x, v.y, v.z, v.w};
    __builtin_nontemporal_store(t, (u32x4*)p);
}

// ---- p1a: per-chunk LDS histogram of coarse buckets + fused h->bf16 convert ----
__global__ void p1a_hist(const int* __restrict__ dst, int* __restrict__ blockCount,
                         const float* __restrict__ h, unsigned* __restrict__ hbf2,
                         long long nd4, int E, int B) {
    __shared__ int lc[256];
    int t = threadIdx.x;
    lc[t] = 0;
    __syncthreads();
    for (long long i = (long long)blockIdx.x * THREADS + t; i < nd4;
         i += (long long)gridDim.x * THREADS) {
        float4 v = ((const float4*)h)[i];
        ((uint2*)hbf2)[i] = make_uint2(f2bf(v.x) | (f2bf(v.y) << 16),
                                       f2bf(v.z) | (f2bf(v.w) << 16));
    }
    int base = blockIdx.x * CHUNK;
    int end = min(base + CHUNK, E);
    int end4 = end >> 2;
    for (int e4 = (base >> 2) + t; e4 < end4; e4 += THREADS) {
        int4 d4 = ((const int4*)dst)[e4];
        atomicAdd(&lc[d4.x >> BKT_BITS], 1);
        atomicAdd(&lc[d4.y >> BKT_BITS], 1);
        atomicAdd(&lc[d4.z >> BKT_BITS], 1);
        atomicAdd(&lc[d4.w >> BKT_BITS], 1);
    }
    for (int e = (end4 << 2) + t; e < end; e += THREADS)
        atomicAdd(&lc[dst[e] >> BKT_BITS], 1);
    __syncthreads();
    if (t < B) blockCount[(long long)blockIdx.x * B + t] = lc[t];
}

// ---- p1b: per-bucket exclusive scan over blocks (in place) + bucket totals ----
__global__ void p1b_scanblocks(int* __restrict__ blockCount, int* __restrict__ total,
                               int NBLK, int B) {
    __shared__ int sm[256];
    int b = blockIdx.x, t = threadIdx.x;
    int run = 0;
    for (int base = 0; base < NBLK; base += 256) {
        int i = base + t;
        int v = (i < NBLK) ? blockCount[(long long)i * B + b] : 0;
        sm[t] = v;
        __syncthreads();
        for (int off = 1; off < 256; off <<= 1) {
            int u = (t >= off) ? sm[t - off] : 0;
            __syncthreads();
            sm[t] += u;
            __syncthreads();
        }
        if (i < NBLK) blockCount[(long long)i * B + b] = run + sm[t] - v;
        run += sm[255];
        __syncthreads();
    }
    if (t == 0) total[b] = run;
}

// ---- p1c: exclusive scan of bucket totals -> bstart[B+1] ----
__global__ void p1c_scanbuckets(const int* __restrict__ total, int* __restrict__ bstart,
                                int B, int E) {
    __shared__ int sm[256];
    int t = threadIdx.x;
    int run = 0;
    for (int base = 0; base < B; base += 256) {
        int i = base + t;
        int v = (i < B) ? total[i] : 0;
        sm[t] = v;
        __syncthreads();
        for (int off = 1; off < 256; off <<= 1) {
            int u = (t >= off) ? sm[t - off] : 0;
            __syncthreads();
            sm[t] += u;
            __syncthreads();
        }
        if (i < B) bstart[i] = run + sm[t] - v;
        run += sm[255];
        __syncthreads();
    }
    if (t == 0) bstart[B] = E;
}

// ---- p1d: scatter edges into bucket-partitioned temp via LDS cursors ----
// temp[pos] = (src | dstlow<<17, w)   [src < 2^17 since N=100k]
__global__ void p1d_scatter(const int* __restrict__ dst, const int* __restrict__ src,
                            const float* __restrict__ w, const int* __restrict__ blockCount,
                            const int* __restrict__ bstart, int2* __restrict__ temp,
                            int E, int B) {
    __shared__ int cur[256];
    int t = threadIdx.x;
    if (t < B) cur[t] = bstart[t] + blockCount[(long long)blockIdx.x * B + t];
    __syncthreads();
    int base = blockIdx.x * CHUNK;
    int end = min(base + CHUNK, E);
    int end4 = end >> 2;
    for (int e4 = (base >> 2) + t; e4 < end4; e4 += THREADS) {
        int4 d4 = ((const int4*)dst)[e4];
        int4 s4 = ((const int4*)src)[e4];
        float4 w4 = ((const float4*)w)[e4];
        int pos;
        pos = atomicAdd(&cur[d4.x >> BKT_BITS], 1);
        temp[pos] = make_int2(s4.x | ((d4.x & (BKT_NODES - 1)) << 17), __float_as_int(w4.x));
        pos = atomicAdd(&cur[d4.y >> BKT_BITS], 1);
        temp[pos] = make_int2(s4.y | ((d4.y & (BKT_NODES - 1)) << 17), __float_as_int(w4.y));
        pos = atomicAdd(&cur[d4.z >> BKT_BITS], 1);
        temp[pos] = make_int2(s4.z | ((d4.z & (BKT_NODES - 1)) << 17), __float_as_int(w4.z));
        pos = atomicAdd(&cur[d4.w >> BKT_BITS], 1);
        temp[pos] = make_int2(s4.w | ((d4.w & (BKT_NODES - 1)) << 17), __float_as_int(w4.w));
    }
    for (int e = (end4 << 2) + t; e < end; e += THREADS) {
        int d = dst[e];
        int pos = atomicAdd(&cur[d >> BKT_BITS], 1);
        temp[pos] = make_int2(src[e] | ((d & (BKT_NODES - 1)) << 17), __float_as_int(w[e]));
    }
}

// ---- pdeg: per-bucket weighted degree (LDS) -> norm ----
__global__ __launch_bounds__(GTHREADS)
void pdeg_norm(const int2* __restrict__ temp, const int* __restrict__ bstart,
               float* __restrict__ norm, int N) {
    __shared__ float degs[BKT_NODES];
    int b = blockIdx.x, t = threadIdx.x;
    degs[t] = 0.0f;
    __syncthreads();
    int ebeg = bstart[b], eend = bstart[b + 1];
    for (int e = ebeg + t; e < eend; e += GTHREADS) {
        int2 pk = temp[e];
        atomicAdd(&degs[(pk.x >> 17) & (BKT_NODES - 1)], __int_as_float(pk.y));
    }
    __syncthreads();
    int node = (b << BKT_BITS) + t;
    if (node < N) norm[node] = rsqrtf(fmaxf(degs[t], 1.0f));
}

// ---- per-edge accumulate into LDS (8 lanes/edge, lane l = dims 8l..8l+7) ----
#define ACC_EDGE(pk, r) do {                                            \
    int dl_ = ((pk).x >> 17) & (BKT_NODES - 1);                         \
    float c_ = __int_as_float((pk).y) * norm[(pk).x & 0x1ffff];         \
    float* a_ = &acc[dl_ * ASTRIDE + (l << 3)];                         \
    float2 fa = bfpair((r).x), fb = bfpair((r).y);                      \
    float2 fc = bfpair((r).z), fd = bfpair((r).w);                      \
    atomicAdd(a_ + 0, fa.x * c_); atomicAdd(a_ + 1, fa.y * c_);         \
    atomicAdd(a_ + 2, fb.x * c_); atomicAdd(a_ + 3, fb.y * c_);         \
    atomicAdd(a_ + 4, fc.x * c_); atomicAdd(a_ + 5, fc.y * c_);         \
    atomicAdd(a_ + 6, fd.x * c_); atomicAdd(a_ + 7, fd.y * c_); } while (0)

// ---- gather layer 1 (LDS-accumulator, per-bucket, no CSR needed) ----
__global__ __launch_bounds__(GTHREADS)
void gather1_acc(const uint4* __restrict__ h_in, const int2* __restrict__ temp,
                 const int* __restrict__ bstart, const float* __restrict__ norm,
                 uint4* __restrict__ h_out, int N) {
    __shared__ float acc[BKT_NODES * ASTRIDE];     // 133,120 B
    int b = blockIdx.x, t = threadIdx.x;
    for (int i = t; i < BKT_NODES * ASTRIDE; i += GTHREADS) acc[i] = 0.0f;
    __syncthreads();
    int ebeg = bstart[b], eend = bstart[b + 1];
    int G = t >> 3, l = t & 7;                     // 64 groups x 8 lanes
    int e = ebeg + G;
    for (; e + 192 < eend; e += 256) {
        int2 p0 = temp[e], p1 = temp[e + 64], p2 = temp[e + 128], p3 = temp[e + 192];
        uint4 r0 = h_in[((long long)(p0.x & 0x1ffff) << 3) + l];
        uint4 r1 = h_in[((long long)(p1.x & 0x1ffff) << 3) + l];
        uint4 r2 = h_in[((long long)(p2.x & 0x1ffff) << 3) + l];
        uint4 r3 = h_in[((long long)(p3.x & 0x1ffff) << 3) + l];
        ACC_EDGE(p0, r0); ACC_EDGE(p1, r1); ACC_EDGE(p2, r2); ACC_EDGE(p3, r3);
    }
    for (; e < eend; e += 64) {
        int2 p = temp[e];
        uint4 r = h_in[((long long)(p.x & 0x1ffff) << 3) + l];
        ACC_EDGE(p, r);
    }
    __syncthreads();
    // epilogue: group G owns nodes G + 64m; lane l packs dims 8l..8l+7
    int node0 = b << BKT_BITS;
    for (int m = 0; m < 8; ++m) {
        int n = (m << 6) + G;
        int node = node0 + n;
        if (node < N) {
            float nv = norm[node];
            const float* a = &acc[n * ASTRIDE + (l << 3)];
            stnt_u4(make_uint4(f2bf(a[0] * nv) | (f2bf(a[1] * nv) << 16),
                               f2bf(a[2] * nv) | (f2bf(a[3] * nv) << 16),
                               f2bf(a[4] * nv) | (f2bf(a[5] * nv) << 16),
                               f2bf(a[6] * nv) | (f2bf(a[7] * nv) << 16)),
                    &h_out[((long long)node << 3) + l]);
        }
    }
}

// ---- gather layer 2 + mean (LDS-accumulator): out = (h0 + h1 + norm*acc)/3 ----
__global__ __launch_bounds__(GTHREADS)
void gather2_acc(const uint4* __restrict__ h0bf, const uint4* __restrict__ h1bf,
                 const int2* __restrict__ temp, const int* __restrict__ bstart,
                 const float* __restrict__ norm, float* __restrict__ out, int N) {
    __shared__ float acc[BKT_NODES * ASTRIDE];
    int b = blockIdx.x, t = threadIdx.x;
    for (int i = t; i < BKT_NODES * ASTRIDE; i += GTHREADS) acc[i] = 0.0f;
    __syncthreads();
    int ebeg = bstart[b], eend = bstart[b + 1];
    int G = t >> 3, l = t & 7;
    int e = ebeg + G;
    for (; e + 192 < eend; e += 256) {
        int2 p0 = temp[e], p1 = temp[e + 64], p2 = temp[e + 128], p3 = temp[e + 192];
        uint4 r0 = h1bf[((long long)(p0.x & 0x1ffff) << 3) + l];
        uint4 r1 = h1bf[((long long)(p1.x & 0x1ffff) << 3) + l];
        uint4 r2 = h1bf[((long long)(p2.x & 0x1ffff) << 3) + l];
        uint4 r3 = h1bf[((long long)(p3.x & 0x1ffff) << 3) + l];
        ACC_EDGE(p0, r0); ACC_EDGE(p1, r1); ACC_EDGE(p2, r2); ACC_EDGE(p3, r3);
    }
    for (; e < eend; e += 64) {
        int2 p = temp[e];
        uint4 r = h1bf[((long long)(p.x & 0x1ffff) << 3) + l];
        ACC_EDGE(p, r);
    }
    __syncthreads();
    int node0 = b << BKT_BITS;
    for (int m = 0; m < 8; ++m) {
        int n = (m << 6) + G;
        int node = node0 + n;
        if (node < N) {
            float nv = norm[node];
            long long idx = ((long long)node << 3) + l;
            uint4 h0r = h0bf[idx], h1r = h1bf[idx];
            float2 h0a = bfpair(h0r.x), h0b = bfpair(h0r.y),
                   h0c = bfpair(h0r.z), h0d = bfpair(h0r.w);
            float2 h1a = bfpair(h1r.x), h1b = bfpair(h1r.y),
                   h1c = bfpair(h1r.z), h1d = bfpair(h1r.w);
            const float* a = &acc[n * ASTRIDE + (l << 3)];
            float4 o0, o1;
            o0.x = (h0a.x + h1a.x + a[0] * nv) * (1.0f / 3.0f);
            o0.y = (h0a.y + h1a.y + a[1] * nv) * (1.0f / 3.0f);
            o0.z = (h0b.x + h1b.x + a[2] * nv) * (1.0f / 3.0f);
            o0.w = (h0b.y + h1b.y + a[3] * nv) * (1.0f / 3.0f);
            o1.x = (h0c.x + h1c.x + a[4] * nv) * (1.0f / 3.0f);
            o1.y = (h0c.y + h1c.y + a[5] * nv) * (1.0f / 3.0f);
            o1.z = (h0d.x + h1d.x + a[6] * nv) * (1.0f / 3.0f);
            o1.w = (h0d.y + h1d.y + a[7] * nv) * (1.0f / 3.0f);
            stnt_f4(o0, &((float4*)out)[((long long)node << 4) + (l << 1)]);
            stnt_f4(o1, &((float4*)out)[((long long)node << 4) + (l << 1) + 1]);
        }
    }
}

extern "C" void kernel_launch(void* const* d_in, const int* in_sizes, int n_in,
                              void* d_out, int out_size, void* d_ws, size_t ws_size,
                              hipStream_t stream) {
    const float* h   = (const float*)d_in[0];
    const float* w   = (const float*)d_in[1];
    const int*   src = (const int*)d_in[2];
    const int*   dst = (const int*)d_in[3];
    const int N = in_sizes[0] / D;   // 100000
    const int E = in_sizes[1];       // 1600000
    float* out = (float*)d_out;

    const int B = (N + BKT_NODES - 1) >> BKT_BITS;   // 196 (<= 256 required)
    const int NBLK = (E + CHUNK - 1) / CHUNK;        // 391

    // ---- workspace layout ----
    char* ws = (char*)d_ws;
    size_t off = 0;
    auto alloc = [&](size_t bytes, size_t align) -> char* {
        off = (off + align - 1) & ~(align - 1);
        char* p = ws + off;
        off += bytes;
        return p;
    };
    float* norm     = (float*)alloc((size_t)N * 4, 16);
    int*   total    = (int*)  alloc((size_t)B * 4, 16);
    int*   bstart   = (int*)  alloc((size_t)(B + 1) * 4, 16);
    int*   blockCnt = (int*)  alloc((size_t)NBLK * B * 4, 16);
    int2*  temp     = (int2*) alloc((size_t)E * 8, 128);
    unsigned* h0bf  = (unsigned*)alloc((size_t)N * D * 2, 128);
    unsigned* h1bf  = (unsigned*)alloc((size_t)N * D * 2, 128);

    const long long nd4 = (long long)N * D / 4;

    // CSR-free build: bucket-partition edges only (no per-node sort)
    p1a_hist<<<NBLK, THREADS, 0, stream>>>(dst, blockCnt, h, h0bf, nd4, E, B);
    p1b_scanblocks<<<B, 256, 0, stream>>>(blockCnt, total, NBLK, B);
    p1c_scanbuckets<<<1, 256, 0, stream>>>(total, bstart, B, E);
    p1d_scatter<<<NBLK, THREADS, 0, stream>>>(dst, src, w, blockCnt, bstart, temp, E, B);
    pdeg_norm<<<B, GTHREADS, 0, stream>>>(temp, bstart, norm, N);

    // gathers: per-bucket LDS fp32 accumulators, unordered edge stream
    gather1_acc<<<B, GTHREADS, 0, stream>>>((const uint4*)h0bf, temp, bstart, norm,
                                            (uint4*)h1bf, N);
    gather2_acc<<<B, GTHREADS, 0, stream>>>((const uint4*)h0bf, (const uint4*)h1bf,
                                            temp, bstart, norm, out, N);
}

// Round 6
// 235.909 us; speedup vs baseline: 6.3657x; 6.3657x over previous
//
#include <hip/hip_runtime.h>
#include <hip/hip_bf16.h>

#define D 64
#define THREADS 256
#define BKT_BITS 9                 // 512 nodes per bucket
#define BKT_NODES (1 << BKT_BITS)
#define CHUNK 4096                 // edges per pass-1 block (391 blocks)

// ---- bf16 helpers (bit tricks, RNE) ----
__device__ __forceinline__ unsigned f2bf(float f) {
    unsigned u = __float_as_uint(f);
    return (u + 0x7fffu + ((u >> 16) & 1u)) >> 16;
}
__device__ __forceinline__ float2 bfpair(unsigned v) {
    return make_float2(__uint_as_float(v << 16), __uint_as_float(v & 0xffff0000u));
}

// ---- non-temporal store wrappers ----
typedef float f32x4 __attribute__((ext_vector_type(4)));
typedef unsigned u32x4 __attribute__((ext_vector_type(4)));
__device__ __forceinline__ void stnt_f4(float4 v, float4* p) {
    f32x4 t = {v.x, v.y, v.z, v.w};
    __builtin_nontemporal_store(t, (f32x4*)p);
}
__device__ __forceinline__ void stnt_u4(uint4 v, uint4* p) {
    u32x4 t = {v.x, v.y, v.z, v.w};
    __builtin_nontemporal_store(t, (u32x4*)p);
}

// ---- p1a: per-chunk LDS histogram of coarse buckets + fused h->bf16 convert ----
__global__ void p1a_hist(const int* __restrict__ dst, int* __restrict__ blockCount,
                         const float* __restrict__ h, unsigned* __restrict__ hbf2,
                         long long nd4, int E, int B) {
    __shared__ int lc[256];
    int t = threadIdx.x;
    lc[t] = 0;
    __syncthreads();
    for (long long i = (long long)blockIdx.x * THREADS + t; i < nd4;
         i += (long long)gridDim.x * THREADS) {
        float4 v = ((const float4*)h)[i];
        ((uint2*)hbf2)[i] = make_uint2(f2bf(v.x) | (f2bf(v.y) << 16),
                                       f2bf(v.z) | (f2bf(v.w) << 16));
    }
    int base = blockIdx.x * CHUNK;
    int end = min(base + CHUNK, E);
    int end4 = end >> 2;
    for (int e4 = (base >> 2) + t; e4 < end4; e4 += THREADS) {
        int4 d4 = ((const int4*)dst)[e4];
        atomicAdd(&lc[d4.x >> BKT_BITS], 1);
        atomicAdd(&lc[d4.y >> BKT_BITS], 1);
        atomicAdd(&lc[d4.z >> BKT_BITS], 1);
        atomicAdd(&lc[d4.w >> BKT_BITS], 1);
    }
    for (int e = (end4 << 2) + t; e < end; e += THREADS)
        atomicAdd(&lc[dst[e] >> BKT_BITS], 1);
    __syncthreads();
    if (t < B) blockCount[(long long)blockIdx.x * B + t] = lc[t];
}

// ---- p1b: per-bucket exclusive scan over blocks (in place) + bucket totals ----
__global__ void p1b_scanblocks(int* __restrict__ blockCount, int* __restrict__ total,
                               int NBLK, int B) {
    __shared__ int sm[256];
    int b = blockIdx.x, t = threadIdx.x;
    int run = 0;
    for (int base = 0; base < NBLK; base += 256) {
        int i = base + t;
        int v = (i < NBLK) ? blockCount[(long long)i * B + b] : 0;
        sm[t] = v;
        __syncthreads();
        for (int off = 1; off < 256; off <<= 1) {
            int u = (t >= off) ? sm[t - off] : 0;
            __syncthreads();
            sm[t] += u;
            __syncthreads();
        }
        if (i < NBLK) blockCount[(long long)i * B + b] = run + sm[t] - v;
        run += sm[255];
        __syncthreads();
    }
    if (t == 0) total[b] = run;
}

// ---- p1c: exclusive scan of bucket totals -> bstart[B+1] ----
__global__ void p1c_scanbuckets(const int* __restrict__ total, int* __restrict__ bstart,
                                int B, int E) {
    __shared__ int sm[256];
    int t = threadIdx.x;
    int run = 0;
    for (int base = 0; base < B; base += 256) {
        int i = base + t;
        int v = (i < B) ? total[i] : 0;
        sm[t] = v;
        __syncthreads();
        for (int off = 1; off < 256; off <<= 1) {
            int u = (t >= off) ? sm[t - off] : 0;
            __syncthreads();
            sm[t] += u;
            __syncthreads();
        }
        if (i < B) bstart[i] = run + sm[t] - v;
        run += sm[255];
        __syncthreads();
    }
    if (t == 0) bstart[B] = E;
}

// ---- p1d: scatter edges into bucket-partitioned temp via LDS cursors ----
// temp[pos] = (src | dstlow<<17, w)   [src < 2^17 since N=100k]
__global__ void p1d_scatter(const int* __restrict__ dst, const int* __restrict__ src,
                            const float* __restrict__ w, const int* __restrict__ blockCount,
                            const int* __restrict__ bstart, int2* __restrict__ temp,
                            int E, int B) {
    __shared__ int cur[256];
    int t = threadIdx.x;
    if (t < B) cur[t] = bstart[t] + blockCount[(long long)blockIdx.x * B + t];
    __syncthreads();
    int base = blockIdx.x * CHUNK;
    int end = min(base + CHUNK, E);
    int end4 = end >> 2;
    for (int e4 = (base >> 2) + t; e4 < end4; e4 += THREADS) {
        int4 d4 = ((const int4*)dst)[e4];
        int4 s4 = ((const int4*)src)[e4];
        float4 w4 = ((const float4*)w)[e4];
        int pos;
        pos = atomicAdd(&cur[d4.x >> BKT_BITS], 1);
        temp[pos] = make_int2(s4.x | ((d4.x & (BKT_NODES - 1)) << 17), __float_as_int(w4.x));
        pos = atomicAdd(&cur[d4.y >> BKT_BITS], 1);
        temp[pos] = make_int2(s4.y | ((d4.y & (BKT_NODES - 1)) << 17), __float_as_int(w4.y));
        pos = atomicAdd(&cur[d4.z >> BKT_BITS], 1);
        temp[pos] = make_int2(s4.z | ((d4.z & (BKT_NODES - 1)) << 17), __float_as_int(w4.z));
        pos = atomicAdd(&cur[d4.w >> BKT_BITS], 1);
        temp[pos] = make_int2(s4.w | ((d4.w & (BKT_NODES - 1)) << 17), __float_as_int(w4.w));
    }
    for (int e = (end4 << 2) + t; e < end; e += THREADS) {
        int d = dst[e];
        int pos = atomicAdd(&cur[d >> BKT_BITS], 1);
        temp[pos] = make_int2(src[e] | ((d & (BKT_NODES - 1)) << 17), __float_as_int(w[e]));
    }
}

// ---- p2: per-bucket CSR finalize + degree-sorted virtual order ----
// vinfo[v] = (row_start, node | deg<<17); gathers iterate v so waves get uniform degree
__global__ void p2_build(const int2* __restrict__ temp, const int* __restrict__ bstart,
                         int2* __restrict__ packed, int2* __restrict__ vinfo,
                         float* __restrict__ norm, int N, int E, int B) {
    __shared__ int cnt[BKT_NODES];
    __shared__ float degs[BKT_NODES];
    __shared__ int cur[BKT_NODES];
    __shared__ int sm[256];
    __shared__ int dbin[64];
    __shared__ int perm[BKT_NODES];
    int b = blockIdx.x, t = threadIdx.x;
    int ebeg = bstart[b], eend = bstart[b + 1];
    for (int i = t; i < BKT_NODES; i += THREADS) { cnt[i] = 0; degs[i] = 0.0f; }
    if (t < 64) dbin[t] = 0;
    __syncthreads();
    for (int e = ebeg + t; e < eend; e += THREADS) {
        int2 pk = temp[e];
        int dl = (pk.x >> 17) & (BKT_NODES - 1);
        atomicAdd(&cnt[dl], 1);
        atomicAdd(&degs[dl], __int_as_float(pk.y));
    }
    __syncthreads();
    // block exclusive scan of cnt[512] -> cur[512]
    int run = 0;
    for (int base = 0; base < BKT_NODES; base += 256) {
        int v = cnt[base + t];
        sm[t] = v;
        __syncthreads();
        for (int off = 1; off < 256; off <<= 1) {
            int u = (t >= off) ? sm[t - off] : 0;
            __syncthreads();
            sm[t] += u;
            __syncthreads();
        }
        cur[base + t] = run + sm[t] - v;
        run += sm[255];
        __syncthreads();
    }
    // norm + degree-bin histogram
    int node0 = b << BKT_BITS;
    for (int i = t; i < BKT_NODES; i += THREADS) {
        int node = node0 + i;
        if (node < N) norm[node] = rsqrtf(fmaxf(degs[i], 1.0f));
        atomicAdd(&dbin[min(cnt[i], 63)], 1);
    }
    __syncthreads();
    if (t == 0) {
        int r = 0;
        for (int k = 0; k < 64; ++k) { int v = dbin[k]; dbin[k] = r; r += v; }
    }
    __syncthreads();
    // counting-sort placement: perm[pos] = node index, ascending degree
    for (int i = t; i < BKT_NODES; i += THREADS) {
        int pos = atomicAdd(&dbin[min(cnt[i], 63)], 1);
        perm[pos] = i;
    }
    __syncthreads();
    // vinfo (uses pristine cur, before placement mutates it)
    for (int v = t; v < BKT_NODES; v += THREADS) {
        int i = perm[v];
        vinfo[node0 + v] = make_int2(ebeg + cur[i], (node0 + i) | (cnt[i] << 17));
    }
    __syncthreads();
    // placement: packed[ebeg + pos] = (src, w)
    for (int e = ebeg + t; e < eend; e += THREADS) {
        int2 pk = temp[e];
        int dl = (pk.x >> 17) & (BKT_NODES - 1);
        int pos = atomicAdd(&cur[dl], 1);                      // LDS atomic w/ return
        packed[ebeg + pos] = make_int2(pk.x & 0x1ffff, pk.y);
    }
}

// 8 bf16 dims per lane per edge; coef = w * norm[src] (norm is L2-resident)
#define EDGE_FMA(r, c, A0, A1, A2, A3, A4, A5, A6, A7) do {            \
    float2 fa = bfpair((r).x), fb = bfpair((r).y);                      \
    float2 fc = bfpair((r).z), fd = bfpair((r).w);                      \
    A0 = fmaf(fa.x, (c), A0); A1 = fmaf(fa.y, (c), A1);                 \
    A2 = fmaf(fb.x, (c), A2); A3 = fmaf(fb.y, (c), A3);                 \
    A4 = fmaf(fc.x, (c), A4); A5 = fmaf(fc.y, (c), A5);                 \
    A6 = fmaf(fd.x, (c), A6); A7 = fmaf(fd.y, (c), A7); } while (0)

// ---- gather layer 1: 8 lanes per virtual node (degree-sorted), unroll 8 ----
__global__ void gather1_kernel(const uint4* __restrict__ h_in, const int2* __restrict__ packed,
                               const int2* __restrict__ vinfo, const float* __restrict__ norm,
                               uint4* __restrict__ h_out, int N) {
    int v = blockIdx.x * (blockDim.x >> 3) + (threadIdx.x >> 3);
    int lane = threadIdx.x & 7;
    int2 vi = vinfo[v];
    int node = vi.y & 0x1ffff;
    int j = vi.x, end = j + (vi.y >> 17);
    float a0 = 0, a1 = 0, a2 = 0, a3 = 0, a4 = 0, a5 = 0, a6 = 0, a7 = 0;
    float b0 = 0, b1 = 0, b2 = 0, b3 = 0, b4 = 0, b5 = 0, b6 = 0, b7 = 0;
    for (; j + 8 <= end; j += 8) {
        int2 p0 = packed[j + 0], p1 = packed[j + 1], p2 = packed[j + 2], p3 = packed[j + 3];
        int2 p4 = packed[j + 4], p5 = packed[j + 5], p6 = packed[j + 6], p7 = packed[j + 7];
        uint4 r0 = h_in[((long long)p0.x << 3) + lane];
        uint4 r1 = h_in[((long long)p1.x << 3) + lane];
        uint4 r2 = h_in[((long long)p2.x << 3) + lane];
        uint4 r3 = h_in[((long long)p3.x << 3) + lane];
        uint4 r4 = h_in[((long long)p4.x << 3) + lane];
        uint4 r5 = h_in[((long long)p5.x << 3) + lane];
        uint4 r6 = h_in[((long long)p6.x << 3) + lane];
        uint4 r7 = h_in[((long long)p7.x << 3) + lane];
        float c0 = __int_as_float(p0.y) * norm[p0.x];
        float c1 = __int_as_float(p1.y) * norm[p1.x];
        float c2 = __int_as_float(p2.y) * norm[p2.x];
        float c3 = __int_as_float(p3.y) * norm[p3.x];
        float c4 = __int_as_float(p4.y) * norm[p4.x];
        float c5 = __int_as_float(p5.y) * norm[p5.x];
        float c6 = __int_as_float(p6.y) * norm[p6.x];
        float c7 = __int_as_float(p7.y) * norm[p7.x];
        EDGE_FMA(r0, c0, a0, a1, a2, a3, a4, a5, a6, a7);
        EDGE_FMA(r1, c1, b0, b1, b2, b3, b4, b5, b6, b7);
        EDGE_FMA(r2, c2, a0, a1, a2, a3, a4, a5, a6, a7);
        EDGE_FMA(r3, c3, b0, b1, b2, b3, b4, b5, b6, b7);
        EDGE_FMA(r4, c4, a0, a1, a2, a3, a4, a5, a6, a7);
        EDGE_FMA(r5, c5, b0, b1, b2, b3, b4, b5, b6, b7);
        EDGE_FMA(r6, c6, a0, a1, a2, a3, a4, a5, a6, a7);
        EDGE_FMA(r7, c7, b0, b1, b2, b3, b4, b5, b6, b7);
    }
    for (; j + 4 <= end; j += 4) {
        int2 p0 = packed[j + 0], p1 = packed[j + 1], p2 = packed[j + 2], p3 = packed[j + 3];
        uint4 r0 = h_in[((long long)p0.x << 3) + lane];
        uint4 r1 = h_in[((long long)p1.x << 3) + lane];
        uint4 r2 = h_in[((long long)p2.x << 3) + lane];
        uint4 r3 = h_in[((long long)p3.x << 3) + lane];
        float c0 = __int_as_float(p0.y) * norm[p0.x];
        float c1 = __int_as_float(p1.y) * norm[p1.x];
        float c2 = __int_as_float(p2.y) * norm[p2.x];
        float c3 = __int_as_float(p3.y) * norm[p3.x];
        EDGE_FMA(r0, c0, a0, a1, a2, a3, a4, a5, a6, a7);
        EDGE_FMA(r1, c1, b0, b1, b2, b3, b4, b5, b6, b7);
        EDGE_FMA(r2, c2, a0, a1, a2, a3, a4, a5, a6, a7);
        EDGE_FMA(r3, c3, b0, b1, b2, b3, b4, b5, b6, b7);
    }
    for (; j < end; ++j) {
        int2 p = packed[j];
        uint4 r = h_in[((long long)p.x << 3) + lane];
        float c = __int_as_float(p.y) * norm[p.x];
        EDGE_FMA(r, c, a0, a1, a2, a3, a4, a5, a6, a7);
    }
    if (node < N) {
        float nv = norm[node];
        float d0 = (a0 + b0) * nv, d1 = (a1 + b1) * nv, d2 = (a2 + b2) * nv, d3 = (a3 + b3) * nv;
        float d4 = (a4 + b4) * nv, d5 = (a5 + b5) * nv, d6 = (a6 + b6) * nv, d7 = (a7 + b7) * nv;
        stnt_u4(make_uint4(f2bf(d0) | (f2bf(d1) << 16), f2bf(d2) | (f2bf(d3) << 16),
                           f2bf(d4) | (f2bf(d5) << 16), f2bf(d6) | (f2bf(d7) << 16)),
                &h_out[((long long)node << 3) + lane]);
    }
}

// ---- gather layer 2 + mean: out = (h0 + h1 + norm*sum h1[src]*coef)/3 ----
__global__ void gather2_final_kernel(const uint4* __restrict__ h0bf, const uint4* __restrict__ h1bf,
                                     const int2* __restrict__ packed, const int2* __restrict__ vinfo,
                                     const float* __restrict__ norm, float* __restrict__ out, int N) {
    int v = blockIdx.x * (blockDim.x >> 3) + (threadIdx.x >> 3);
    int lane = threadIdx.x & 7;
    int2 vi = vinfo[v];
    int node = vi.y & 0x1ffff;
    int j = vi.x, end = j + (vi.y >> 17);
    float a0 = 0, a1 = 0, a2 = 0, a3 = 0, a4 = 0, a5 = 0, a6 = 0, a7 = 0;
    float b0 = 0, b1 = 0, b2 = 0, b3 = 0, b4 = 0, b5 = 0, b6 = 0, b7 = 0;
    for (; j + 8 <= end; j += 8) {
        int2 p0 = packed[j + 0], p1 = packed[j + 1], p2 = packed[j + 2], p3 = packed[j + 3];
        int2 p4 = packed[j + 4], p5 = packed[j + 5], p6 = packed[j + 6], p7 = packed[j + 7];
        uint4 r0 = h1bf[((long long)p0.x << 3) + lane];
        uint4 r1 = h1bf[((long long)p1.x << 3) + lane];
        uint4 r2 = h1bf[((long long)p2.x << 3) + lane];
        uint4 r3 = h1bf[((long long)p3.x << 3) + lane];
        uint4 r4 = h1bf[((long long)p4.x << 3) + lane];
        uint4 r5 = h1bf[((long long)p5.x << 3) + lane];
        uint4 r6 = h1bf[((long long)p6.x << 3) + lane];
        uint4 r7 = h1bf[((long long)p7.x << 3) + lane];
        float c0 = __int_as_float(p0.y) * norm[p0.x];
        float c1 = __int_as_float(p1.y) * norm[p1.x];
        float c2 = __int_as_float(p2.y) * norm[p2.x];
        float c3 = __int_as_float(p3.y) * norm[p3.x];
        float c4 = __int_as_float(p4.y) * norm[p4.x];
        float c5 = __int_as_float(p5.y) * norm[p5.x];
        float c6 = __int_as_float(p6.y) * norm[p6.x];
        float c7 = __int_as_float(p7.y) * norm[p7.x];
        EDGE_FMA(r0, c0, a0, a1, a2, a3, a4, a5, a6, a7);
        EDGE_FMA(r1, c1, b0, b1, b2, b3, b4, b5, b6, b7);
        EDGE_FMA(r2, c2, a0, a1, a2, a3, a4, a5, a6, a7);
        EDGE_FMA(r3, c3, b0, b1, b2, b3, b4, b5, b6, b7);
        EDGE_FMA(r4, c4, a0, a1, a2, a3, a4, a5, a6, a7);
        EDGE_FMA(r5, c5, b0, b1, b2, b3, b4, b5, b6, b7);
        EDGE_FMA(r6, c6, a0, a1, a2, a3, a4, a5, a6, a7);
        EDGE_FMA(r7, c7, b0, b1, b2, b3, b4, b5, b6, b7);
    }
    for (; j + 4 <= end; j += 4) {
        int2 p0 = packed[j + 0], p1 = packed[j + 1], p2 = packed[j + 2], p3 = packed[j + 3];
        uint4 r0 = h1bf[((long long)p0.x << 3) + lane];
        uint4 r1 = h1bf[((long long)p1.x << 3) + lane];
        uint4 r2 = h1bf[((long long)p2.x << 3) + lane];
        uint4 r3 = h1bf[((long long)p3.x << 3) + lane];
        float c0 = __int_as_float(p0.y) * norm[p0.x];
        float c1 = __int_as_float(p1.y) * norm[p1.x];
        float c2 = __int_as_float(p2.y) * norm[p2.x];
        float c3 = __int_as_float(p3.y) * norm[p3.x];
        EDGE_FMA(r0, c0, a0, a1, a2, a3, a4, a5, a6, a7);
        EDGE_FMA(r1, c1, b0, b1, b2, b3, b4, b5, b6, b7);
        EDGE_FMA(r2, c2, a0, a1, a2, a3, a4, a5, a6, a7);
        EDGE_FMA(r3, c3, b0, b1, b2, b3, b4, b5, b6, b7);
    }
    for (; j < end; ++j) {
        int2 p = packed[j];
        uint4 r = h1bf[((long long)p.x << 3) + lane];
        float c = __int_as_float(p.y) * norm[p.x];
        EDGE_FMA(r, c, a0, a1, a2, a3, a4, a5, a6, a7);
    }
    if (node < N) {
        long long idx = ((long long)node << 3) + lane;
        float nv = norm[node];
        uint4 h0r = h0bf[idx];
        uint4 h1r = h1bf[idx];
        float2 h0a = bfpair(h0r.x), h0b = bfpair(h0r.y), h0c = bfpair(h0r.z), h0d = bfpair(h0r.w);
        float2 h1a = bfpair(h1r.x), h1b = bfpair(h1r.y), h1c = bfpair(h1r.z), h1d = bfpair(h1r.w);
        float4 o0, o1;
        o0.x = (h0a.x + h1a.x + (a0 + b0) * nv) * (1.0f / 3.0f);
        o0.y = (h0a.y + h1a.y + (a1 + b1) * nv) * (1.0f / 3.0f);
        o0.z = (h0b.x + h1b.x + (a2 + b2) * nv) * (1.0f / 3.0f);
        o0.w = (h0b.y + h1b.y + (a3 + b3) * nv) * (1.0f / 3.0f);
        o1.x = (h0c.x + h1c.x + (a4 + b4) * nv) * (1.0f / 3.0f);
        o1.y = (h0c.y + h1c.y + (a5 + b5) * nv) * (1.0f / 3.0f);
        o1.z = (h0d.x + h1d.x + (a6 + b6) * nv) * (1.0f / 3.0f);
        o1.w = (h0d.y + h1d.y + (a7 + b7) * nv) * (1.0f / 3.0f);
        stnt_f4(o0, &((float4*)out)[((long long)node << 4) + (lane << 1)]);
        stnt_f4(o1, &((float4*)out)[((long long)node << 4) + (lane << 1) + 1]);
    }
}

extern "C" void kernel_launch(void* const* d_in, const int* in_sizes, int n_in,
                              void* d_out, int out_size, void* d_ws, size_t ws_size,
                              hipStream_t stream) {
    const float* h   = (const float*)d_in[0];
    const float* w   = (const float*)d_in[1];
    const int*   src = (const int*)d_in[2];
    const int*   dst = (const int*)d_in[3];
    const int N = in_sizes[0] / D;   // 100000
    const int E = in_sizes[1];       // 1600000
    float* out = (float*)d_out;

    const int B = (N + BKT_NODES - 1) >> BKT_BITS;   // 196 (<= 256 required)
    const int NPAD = B << BKT_BITS;                  // 100352
    const int NBLK = (E + CHUNK - 1) / CHUNK;        // 391

    // ---- workspace layout ----
    char* ws = (char*)d_ws;
    size_t off = 0;
    auto alloc = [&](size_t bytes, size_t align) -> char* {
        off = (off + align - 1) & ~(align - 1);
        char* p = ws + off;
        off += bytes;
        return p;
    };
    float* norm     = (float*)alloc((size_t)N * 4, 16);
    int*   total    = (int*)  alloc((size_t)B * 4, 16);
    int*   bstart   = (int*)  alloc((size_t)(B + 1) * 4, 16);
    int*   blockCnt = (int*)  alloc((size_t)NBLK * B * 4, 16);
    int2*  vinfo    = (int2*) alloc((size_t)NPAD * 8, 16);
    int2*  packed   = (int2*) alloc((size_t)E * 8, 128);
    // temp (build phase) time-shares with h1bf (gather phase), both 12.8 MB
    char*  shared_region = alloc((size_t)E * 8, 128);
    int2*     temp = (int2*)shared_region;
    unsigned* h1bf = (unsigned*)shared_region;
    unsigned* h0bf = (unsigned*)alloc((size_t)N * D * 2, 128);

    const int nodes_per_block = THREADS / 8;         // 32 virtual nodes per block
    const int gather_blocks = NPAD / nodes_per_block; // 3136 (NPAD % 32 == 0)
    const long long nd4 = (long long)N * D / 4;

    // CSR build: LDS counting sort + degree-sorted virtual order; tobf16 fused in p1a
    p1a_hist<<<NBLK, THREADS, 0, stream>>>(dst, blockCnt, h, h0bf, nd4, E, B);
    p1b_scanblocks<<<B, 256, 0, stream>>>(blockCnt, total, NBLK, B);
    p1c_scanbuckets<<<1, 256, 0, stream>>>(total, bstart, B, E);
    p1d_scatter<<<NBLK, THREADS, 0, stream>>>(dst, src, w, blockCnt, bstart, temp, E, B);
    p2_build<<<B, 256, 0, stream>>>(temp, bstart, packed, vinfo, norm, N, E, B);

    // gathers (8-lane/uint4 unroll-8; degree-uniform waves via vinfo)
    gather1_kernel<<<gather_blocks, THREADS, 0, stream>>>((const uint4*)h0bf, packed, vinfo,
                                                          norm, (uint4*)h1bf, N);
    gather2_final_kernel<<<gather_blocks, THREADS, 0, stream>>>((const uint4*)h0bf, (const uint4*)h1bf,
                                                                packed, vinfo, norm, out, N);
}

// Round 7
// 212.898 us; speedup vs baseline: 7.0537x; 1.1081x over previous
//
#include <hip/hip_runtime.h>
#include <hip/hip_bf16.h>

#define D 64
#define THREADS 256
#define P2T 1024                   // p2_build block size (16 waves/CU)
#define BKT_BITS 9                 // 512 nodes per bucket
#define BKT_NODES (1 << BKT_BITS)
#define CHUNK 2048                 // edges per pass-1 block (782 blocks, ~3/CU)

// ---- bf16 helpers (bit tricks, RNE) ----
__device__ __forceinline__ unsigned f2bf(float f) {
    unsigned u = __float_as_uint(f);
    return (u + 0x7fffu + ((u >> 16) & 1u)) >> 16;
}
__device__ __forceinline__ float2 bfpair(unsigned v) {
    return make_float2(__uint_as_float(v << 16), __uint_as_float(v & 0xffff0000u));
}

// ---- non-temporal store wrappers ----
typedef float f32x4 __attribute__((ext_vector_type(4)));
typedef unsigned u32x4 __attribute__((ext_vector_type(4)));
__device__ __forceinline__ void stnt_f4(float4 v, float4* p) {
    f32x4 t = {v.x, v.y, v.z, v.w};
    __builtin_nontemporal_store(t, (f32x4*)p);
}
__device__ __forceinline__ void stnt_u4(uint4 v, uint4* p) {
    u32x4 t = {v.x, v.y, v.z, v.w};
    __builtin_nontemporal_store(t, (u32x4*)p);
}

// ---- p1a: per-chunk LDS histogram of coarse buckets + fused h->bf16 convert ----
__global__ void p1a_hist(const int* __restrict__ dst, int* __restrict__ blockCount,
                         const float* __restrict__ h, unsigned* __restrict__ hbf2,
                         long long nd4, int E, int B) {
    __shared__ int lc[256];
    int t = threadIdx.x;
    lc[t] = 0;
    __syncthreads();
    for (long long i = (long long)blockIdx.x * THREADS + t; i < nd4;
         i += (long long)gridDim.x * THREADS) {
        float4 v = ((const float4*)h)[i];
        ((uint2*)hbf2)[i] = make_uint2(f2bf(v.x) | (f2bf(v.y) << 16),
                                       f2bf(v.z) | (f2bf(v.w) << 16));
    }
    int base = blockIdx.x * CHUNK;
    int end = min(base + CHUNK, E);
    int end4 = end >> 2;
    for (int e4 = (base >> 2) + t; e4 < end4; e4 += THREADS) {
        int4 d4 = ((const int4*)dst)[e4];
        atomicAdd(&lc[d4.x >> BKT_BITS], 1);
        atomicAdd(&lc[d4.y >> BKT_BITS], 1);
        atomicAdd(&lc[d4.z >> BKT_BITS], 1);
        atomicAdd(&lc[d4.w >> BKT_BITS], 1);
    }
    for (int e = (end4 << 2) + t; e < end; e += THREADS)
        atomicAdd(&lc[dst[e] >> BKT_BITS], 1);
    __syncthreads();
    if (t < B) blockCount[(long long)blockIdx.x * B + t] = lc[t];
}

// ---- p1b: per-bucket exclusive scan over blocks (in place) + bucket totals ----
__global__ void p1b_scanblocks(int* __restrict__ blockCount, int* __restrict__ total,
                               int NBLK, int B) {
    __shared__ int sm[512];
    int b = blockIdx.x, t = threadIdx.x;    // 512 threads
    int run = 0;
    for (int base = 0; base < NBLK; base += 512) {
        int i = base + t;
        int v = (i < NBLK) ? blockCount[(long long)i * B + b] : 0;
        sm[t] = v;
        __syncthreads();
        for (int off = 1; off < 512; off <<= 1) {
            int u = (t >= off) ? sm[t - off] : 0;
            __syncthreads();
            sm[t] += u;
            __syncthreads();
        }
        if (i < NBLK) blockCount[(long long)i * B + b] = run + sm[t] - v;
        run += sm[511];
        __syncthreads();
    }
    if (t == 0) total[b] = run;
}

// ---- p1c: exclusive scan of bucket totals -> bstart[B+1] ----
__global__ void p1c_scanbuckets(const int* __restrict__ total, int* __restrict__ bstart,
                                int B, int E) {
    __shared__ int sm[256];
    int t = threadIdx.x;
    int run = 0;
    for (int base = 0; base < B; base += 256) {
        int i = base + t;
        int v = (i < B) ? total[i] : 0;
        sm[t] = v;
        __syncthreads();
        for (int off = 1; off < 256; off <<= 1) {
            int u = (t >= off) ? sm[t - off] : 0;
            __syncthreads();
            sm[t] += u;
            __syncthreads();
        }
        if (i < B) bstart[i] = run + sm[t] - v;
        run += sm[255];
        __syncthreads();
    }
    if (t == 0) bstart[B] = E;
}

// ---- p1d: scatter edges into bucket-partitioned temp via LDS cursors ----
// temp[pos] = (src | dstlow<<17, w)   [src < 2^17 since N=100k]
__global__ void p1d_scatter(const int* __restrict__ dst, const int* __restrict__ src,
                            const float* __restrict__ w, const int* __restrict__ blockCount,
                            const int* __restrict__ bstart, int2* __restrict__ temp,
                            int E, int B) {
    __shared__ int cur[256];
    int t = threadIdx.x;
    if (t < B) cur[t] = bstart[t] + blockCount[(long long)blockIdx.x * B + t];
    __syncthreads();
    int base = blockIdx.x * CHUNK;
    int end = min(base + CHUNK, E);
    int end4 = end >> 2;
    for (int e4 = (base >> 2) + t; e4 < end4; e4 += THREADS) {
        int4 d4 = ((const int4*)dst)[e4];
        int4 s4 = ((const int4*)src)[e4];
        float4 w4 = ((const float4*)w)[e4];
        int pos;
        pos = atomicAdd(&cur[d4.x >> BKT_BITS], 1);
        temp[pos] = make_int2(s4.x | ((d4.x & (BKT_NODES - 1)) << 17), __float_as_int(w4.x));
        pos = atomicAdd(&cur[d4.y >> BKT_BITS], 1);
        temp[pos] = make_int2(s4.y | ((d4.y & (BKT_NODES - 1)) << 17), __float_as_int(w4.y));
        pos = atomicAdd(&cur[d4.z >> BKT_BITS], 1);
        temp[pos] = make_int2(s4.z | ((d4.z & (BKT_NODES - 1)) << 17), __float_as_int(w4.z));
        pos = atomicAdd(&cur[d4.w >> BKT_BITS], 1);
        temp[pos] = make_int2(s4.w | ((d4.w & (BKT_NODES - 1)) << 17), __float_as_int(w4.w));
    }
    for (int e = (end4 << 2) + t; e < end; e += THREADS) {
        int d = dst[e];
        int pos = atomicAdd(&cur[d >> BKT_BITS], 1);
        temp[pos] = make_int2(src[e] | ((d & (BKT_NODES - 1)) << 17), __float_as_int(w[e]));
    }
}

// ---- p2: per-bucket CSR finalize, 1024 threads (16 waves/CU) ----
// histogram+deg (LDS) -> single 512-thread scan -> rowptr/norm -> placement
__global__ __launch_bounds__(P2T)
void p2_build(const int2* __restrict__ temp, const int* __restrict__ bstart,
              int2* __restrict__ packed, int* __restrict__ rowptr,
              float* __restrict__ norm, int N, int E, int B) {
    __shared__ int cnt[BKT_NODES];
    __shared__ float degs[BKT_NODES];
    __shared__ int cur[BKT_NODES];
    __shared__ int sm[BKT_NODES];
    int b = blockIdx.x, t = threadIdx.x;
    int ebeg = bstart[b], eend = bstart[b + 1];
    if (t < BKT_NODES) { cnt[t] = 0; degs[t] = 0.0f; }
    __syncthreads();
    for (int e = ebeg + t; e < eend; e += P2T) {
        int2 pk = temp[e];
        int dl = (pk.x >> 17) & (BKT_NODES - 1);
        atomicAdd(&cnt[dl], 1);
        atomicAdd(&degs[dl], __int_as_float(pk.y));
    }
    __syncthreads();
    // single-tile exclusive scan of cnt[512] using 512 threads
    int v0 = 0;
    if (t < BKT_NODES) { v0 = cnt[t]; sm[t] = v0; }
    __syncthreads();
    for (int off = 1; off < BKT_NODES; off <<= 1) {
        int u = (t >= off && t < BKT_NODES) ? sm[t - off] : 0;
        __syncthreads();
        if (t < BKT_NODES) sm[t] += u;
        __syncthreads();
    }
    int node0 = b << BKT_BITS;
    if (t < BKT_NODES) {
        cur[t] = sm[t] - v0;                   // exclusive, bucket-local
        int node = node0 + t;
        if (node < N) {
            rowptr[node] = ebeg + cur[t];
            norm[node] = rsqrtf(fmaxf(degs[t], 1.0f));
        }
    }
    if (b == 0 && t == 0) rowptr[N] = E;
    __syncthreads();
    // placement: packed[ebeg + pos] = (src, w)
    for (int e = ebeg + t; e < eend; e += P2T) {
        int2 pk = temp[e];
        int dl = (pk.x >> 17) & (BKT_NODES - 1);
        int pos = atomicAdd(&cur[dl], 1);                      // LDS atomic w/ return
        packed[ebeg + pos] = make_int2(pk.x & 0x1ffff, pk.y);
    }
}

// 8 bf16 dims per lane per edge; coef = w * norm[src] (norm is L2-resident)
#define EDGE_FMA(r, c, A0, A1, A2, A3, A4, A5, A6, A7) do {            \
    float2 fa = bfpair((r).x), fb = bfpair((r).y);                      \
    float2 fc = bfpair((r).z), fd = bfpair((r).w);                      \
    A0 = fmaf(fa.x, (c), A0); A1 = fmaf(fa.y, (c), A1);                 \
    A2 = fmaf(fb.x, (c), A2); A3 = fmaf(fb.y, (c), A3);                 \
    A4 = fmaf(fc.x, (c), A4); A5 = fmaf(fc.y, (c), A5);                 \
    A6 = fmaf(fd.x, (c), A6); A7 = fmaf(fd.y, (c), A7); } while (0)

// ---- gather layer 1: 8 lanes per node (lane = 8 dims, uint4), unroll 8 ----
__global__ void gather1_kernel(const uint4* __restrict__ h_in, const int2* __restrict__ packed,
                               const int* __restrict__ rowptr, const float* __restrict__ norm,
                               uint4* __restrict__ h_out, int N) {
    int node = blockIdx.x * (blockDim.x >> 3) + (threadIdx.x >> 3);
    int lane = threadIdx.x & 7;
    if (node >= N) return;
    int j = rowptr[node], end = rowptr[node + 1];
    float a0 = 0, a1 = 0, a2 = 0, a3 = 0, a4 = 0, a5 = 0, a6 = 0, a7 = 0;
    float b0 = 0, b1 = 0, b2 = 0, b3 = 0, b4 = 0, b5 = 0, b6 = 0, b7 = 0;
    for (; j + 8 <= end; j += 8) {
        int2 p0 = packed[j + 0], p1 = packed[j + 1], p2 = packed[j + 2], p3 = packed[j + 3];
        int2 p4 = packed[j + 4], p5 = packed[j + 5], p6 = packed[j + 6], p7 = packed[j + 7];
        uint4 r0 = h_in[((long long)p0.x << 3) + lane];
        uint4 r1 = h_in[((long long)p1.x << 3) + lane];
        uint4 r2 = h_in[((long long)p2.x << 3) + lane];
        uint4 r3 = h_in[((long long)p3.x << 3) + lane];
        uint4 r4 = h_in[((long long)p4.x << 3) + lane];
        uint4 r5 = h_in[((long long)p5.x << 3) + lane];
        uint4 r6 = h_in[((long long)p6.x << 3) + lane];
        uint4 r7 = h_in[((long long)p7.x << 3) + lane];
        float c0 = __int_as_float(p0.y) * norm[p0.x];
        float c1 = __int_as_float(p1.y) * norm[p1.x];
        float c2 = __int_as_float(p2.y) * norm[p2.x];
        float c3 = __int_as_float(p3.y) * norm[p3.x];
        float c4 = __int_as_float(p4.y) * norm[p4.x];
        float c5 = __int_as_float(p5.y) * norm[p5.x];
        float c6 = __int_as_float(p6.y) * norm[p6.x];
        float c7 = __int_as_float(p7.y) * norm[p7.x];
        EDGE_FMA(r0, c0, a0, a1, a2, a3, a4, a5, a6, a7);
        EDGE_FMA(r1, c1, b0, b1, b2, b3, b4, b5, b6, b7);
        EDGE_FMA(r2, c2, a0, a1, a2, a3, a4, a5, a6, a7);
        EDGE_FMA(r3, c3, b0, b1, b2, b3, b4, b5, b6, b7);
        EDGE_FMA(r4, c4, a0, a1, a2, a3, a4, a5, a6, a7);
        EDGE_FMA(r5, c5, b0, b1, b2, b3, b4, b5, b6, b7);
        EDGE_FMA(r6, c6, a0, a1, a2, a3, a4, a5, a6, a7);
        EDGE_FMA(r7, c7, b0, b1, b2, b3, b4, b5, b6, b7);
    }
    for (; j + 4 <= end; j += 4) {
        int2 p0 = packed[j + 0], p1 = packed[j + 1], p2 = packed[j + 2], p3 = packed[j + 3];
        uint4 r0 = h_in[((long long)p0.x << 3) + lane];
        uint4 r1 = h_in[((long long)p1.x << 3) + lane];
        uint4 r2 = h_in[((long long)p2.x << 3) + lane];
        uint4 r3 = h_in[((long long)p3.x << 3) + lane];
        float c0 = __int_as_float(p0.y) * norm[p0.x];
        float c1 = __int_as_float(p1.y) * norm[p1.x];
        float c2 = __int_as_float(p2.y) * norm[p2.x];
        float c3 = __int_as_float(p3.y) * norm[p3.x];
        EDGE_FMA(r0, c0, a0, a1, a2, a3, a4, a5, a6, a7);
        EDGE_FMA(r1, c1, b0, b1, b2, b3, b4, b5, b6, b7);
        EDGE_FMA(r2, c2, a0, a1, a2, a3, a4, a5, a6, a7);
        EDGE_FMA(r3, c3, b0, b1, b2, b3, b4, b5, b6, b7);
    }
    for (; j < end; ++j) {
        int2 p = packed[j];
        uint4 r = h_in[((long long)p.x << 3) + lane];
        float c = __int_as_float(p.y) * norm[p.x];
        EDGE_FMA(r, c, a0, a1, a2, a3, a4, a5, a6, a7);
    }
    float nv = norm[node];
    float d0 = (a0 + b0) * nv, d1 = (a1 + b1) * nv, d2 = (a2 + b2) * nv, d3 = (a3 + b3) * nv;
    float d4 = (a4 + b4) * nv, d5 = (a5 + b5) * nv, d6 = (a6 + b6) * nv, d7 = (a7 + b7) * nv;
    stnt_u4(make_uint4(f2bf(d0) | (f2bf(d1) << 16), f2bf(d2) | (f2bf(d3) << 16),
                       f2bf(d4) | (f2bf(d5) << 16), f2bf(d6) | (f2bf(d7) << 16)),
            &h_out[((long long)node << 3) + lane]);
}

// ---- gather layer 2 + mean: out = (h0 + h1 + norm*sum h1[src]*coef)/3 ----
__global__ void gather2_final_kernel(const uint4* __restrict__ h0bf, const uint4* __restrict__ h1bf,
                                     const int2* __restrict__ packed, const int* __restrict__ rowptr,
                                     const float* __restrict__ norm, float* __restrict__ out, int N) {
    int node = blockIdx.x * (blockDim.x >> 3) + (threadIdx.x >> 3);
    int lane = threadIdx.x & 7;
    if (node >= N) return;
    int j = rowptr[node], end = rowptr[node + 1];
    float a0 = 0, a1 = 0, a2 = 0, a3 = 0, a4 = 0, a5 = 0, a6 = 0, a7 = 0;
    float b0 = 0, b1 = 0, b2 = 0, b3 = 0, b4 = 0, b5 = 0, b6 = 0, b7 = 0;
    for (; j + 8 <= end; j += 8) {
        int2 p0 = packed[j + 0], p1 = packed[j + 1], p2 = packed[j + 2], p3 = packed[j + 3];
        int2 p4 = packed[j + 4], p5 = packed[j + 5], p6 = packed[j + 6], p7 = packed[j + 7];
        uint4 r0 = h1bf[((long long)p0.x << 3) + lane];
        uint4 r1 = h1bf[((long long)p1.x << 3) + lane];
        uint4 r2 = h1bf[((long long)p2.x << 3) + lane];
        uint4 r3 = h1bf[((long long)p3.x << 3) + lane];
        uint4 r4 = h1bf[((long long)p4.x << 3) + lane];
        uint4 r5 = h1bf[((long long)p5.x << 3) + lane];
        uint4 r6 = h1bf[((long long)p6.x << 3) + lane];
        uint4 r7 = h1bf[((long long)p7.x << 3) + lane];
        float c0 = __int_as_float(p0.y) * norm[p0.x];
        float c1 = __int_as_float(p1.y) * norm[p1.x];
        float c2 = __int_as_float(p2.y) * norm[p2.x];
        float c3 = __int_as_float(p3.y) * norm[p3.x];
        float c4 = __int_as_float(p4.y) * norm[p4.x];
        float c5 = __int_as_float(p5.y) * norm[p5.x];
        float c6 = __int_as_float(p6.y) * norm[p6.x];
        float c7 = __int_as_float(p7.y) * norm[p7.x];
        EDGE_FMA(r0, c0, a0, a1, a2, a3, a4, a5, a6, a7);
        EDGE_FMA(r1, c1, b0, b1, b2, b3, b4, b5, b6, b7);
        EDGE_FMA(r2, c2, a0, a1, a2, a3, a4, a5, a6, a7);
        EDGE_FMA(r3, c3, b0, b1, b2, b3, b4, b5, b6, b7);
        EDGE_FMA(r4, c4, a0, a1, a2, a3, a4, a5, a6, a7);
        EDGE_FMA(r5, c5, b0, b1, b2, b3, b4, b5, b6, b7);
        EDGE_FMA(r6, c6, a0, a1, a2, a3, a4, a5, a6, a7);
        EDGE_FMA(r7, c7, b0, b1, b2, b3, b4, b5, b6, b7);
    }
    for (; j + 4 <= end; j += 4) {
        int2 p0 = packed[j + 0], p1 = packed[j + 1], p2 = packed[j + 2], p3 = packed[j + 3];
        uint4 r0 = h1bf[((long long)p0.x << 3) + lane];
        uint4 r1 = h1bf[((long long)p1.x << 3) + lane];
        uint4 r2 = h1bf[((long long)p2.x << 3) + lane];
        uint4 r3 = h1bf[((long long)p3.x << 3) + lane];
        float c0 = __int_as_float(p0.y) * norm[p0.x];
        float c1 = __int_as_float(p1.y) * norm[p1.x];
        float c2 = __int_as_float(p2.y) * norm[p2.x];
        float c3 = __int_as_float(p3.y) * norm[p3.x];
        EDGE_FMA(r0, c0, a0, a1, a2, a3, a4, a5, a6, a7);
        EDGE_FMA(r1, c1, b0, b1, b2, b3, b4, b5, b6, b7);
        EDGE_FMA(r2, c2, a0, a1, a2, a3, a4, a5, a6, a7);
        EDGE_FMA(r3, c3, b0, b1, b2, b3, b4, b5, b6, b7);
    }
    for (; j < end; ++j) {
        int2 p = packed[j];
        uint4 r = h1bf[((long long)p.x << 3) + lane];
        float c = __int_as_float(p.y) * norm[p.x];
        EDGE_FMA(r, c, a0, a1, a2, a3, a4, a5, a6, a7);
    }
    long long idx = ((long long)node << 3) + lane;
    float nv = norm[node];
    uint4 h0r = h0bf[idx];
    uint4 h1r = h1bf[idx];
    float2 h0a = bfpair(h0r.x), h0b = bfpair(h0r.y), h0c = bfpair(h0r.z), h0d = bfpair(h0r.w);
    float2 h1a = bfpair(h1r.x), h1b = bfpair(h1r.y), h1c = bfpair(h1r.z), h1d = bfpair(h1r.w);
    float4 o0, o1;
    o0.x = (h0a.x + h1a.x + (a0 + b0) * nv) * (1.0f / 3.0f);
    o0.y = (h0a.y + h1a.y + (a1 + b1) * nv) * (1.0f / 3.0f);
    o0.z = (h0b.x + h1b.x + (a2 + b2) * nv) * (1.0f / 3.0f);
    o0.w = (h0b.y + h1b.y + (a3 + b3) * nv) * (1.0f / 3.0f);
    o1.x = (h0c.x + h1c.x + (a4 + b4) * nv) * (1.0f / 3.0f);
    o1.y = (h0c.y + h1c.y + (a5 + b5) * nv) * (1.0f / 3.0f);
    o1.z = (h0d.x + h1d.x + (a6 + b6) * nv) * (1.0f / 3.0f);
    o1.w = (h0d.y + h1d.y + (a7 + b7) * nv) * (1.0f / 3.0f);
    stnt_f4(o0, &((float4*)out)[((long long)node << 4) + (lane << 1)]);
    stnt_f4(o1, &((float4*)out)[((long long)node << 4) + (lane << 1) + 1]);
}

extern "C" void kernel_launch(void* const* d_in, const int* in_sizes, int n_in,
                              void* d_out, int out_size, void* d_ws, size_t ws_size,
                              hipStream_t stream) {
    const float* h   = (const float*)d_in[0];
    const float* w   = (const float*)d_in[1];
    const int*   src = (const int*)d_in[2];
    const int*   dst = (const int*)d_in[3];
    const int N = in_sizes[0] / D;   // 100000
    const int E = in_sizes[1];       // 1600000
    float* out = (float*)d_out;

    const int B = (N + BKT_NODES - 1) >> BKT_BITS;   // 196 (<= 256 required)
    const int NBLK = (E + CHUNK - 1) / CHUNK;        // 782

    // ---- workspace layout ----
    char* ws = (char*)d_ws;
    size_t off = 0;
    auto alloc = [&](size_t bytes, size_t align) -> char* {
        off = (off + align - 1) & ~(align - 1);
        char* p = ws + off;
        off += bytes;
        return p;
    };
    float* norm     = (float*)alloc((size_t)N * 4, 16);
    int*   rowptr   = (int*)  alloc((size_t)(N + 1) * 4, 16);
    int*   total    = (int*)  alloc((size_t)B * 4, 16);
    int*   bstart   = (int*)  alloc((size_t)(B + 1) * 4, 16);
    int*   blockCnt = (int*)  alloc((size_t)NBLK * B * 4, 16);
    int2*  packed   = (int2*) alloc((size_t)E * 8, 128);
    // temp (build phase) time-shares with h1bf (gather phase), both 12.8 MB
    char*  shared_region = alloc((size_t)E * 8, 128);
    int2*     temp = (int2*)shared_region;
    unsigned* h1bf = (unsigned*)shared_region;
    unsigned* h0bf = (unsigned*)alloc((size_t)N * D * 2, 128);

    const int nodes_per_block = THREADS / 8;         // 8 lanes per node
    const int gather_blocks = (N + nodes_per_block - 1) / nodes_per_block;
    const long long nd4 = (long long)N * D / 4;

    // CSR build: LDS counting sort (2 passes); tobf16 fused in p1a
    p1a_hist<<<NBLK, THREADS, 0, stream>>>(dst, blockCnt, h, h0bf, nd4, E, B);
    p1b_scanblocks<<<B, 512, 0, stream>>>(blockCnt, total, NBLK, B);
    p1c_scanbuckets<<<1, 256, 0, stream>>>(total, bstart, B, E);
    p1d_scatter<<<NBLK, THREADS, 0, stream>>>(dst, src, w, blockCnt, bstart, temp, E, B);
    p2_build<<<B, P2T, 0, stream>>>(temp, bstart, packed, rowptr, norm, N, E, B);

    // gathers (8-lane/uint4 unroll-8; norm L2-resident; nt stores on streams)
    gather1_kernel<<<gather_blocks, THREADS, 0, stream>>>((const uint4*)h0bf, packed, rowptr,
                                                          norm, (uint4*)h1bf, N);
    gather2_final_kernel<<<gather_blocks, THREADS, 0, stream>>>((const uint4*)h0bf, (const uint4*)h1bf,
                                                                packed, rowptr, norm, out, N);
}